// Round 8
// baseline (1489.355 us; speedup 1.0000x reference)
//
#include <hip/hip_runtime.h>
#include <math.h>

#define BB 64
#define TT 1024
#define II 256
#define HD 256

typedef unsigned short ushort_t;
typedef unsigned int uint_t;

// MFMA fragment types
typedef short sh8 __attribute__((ext_vector_type(8)));
typedef float fx4 __attribute__((ext_vector_type(4)));

// ---- bf16 helpers (manual, RNE) -------------------------------------------
__device__ __forceinline__ ushort_t f2bf(float f) {
    uint_t u = __float_as_uint(f);
    uint_t r = (u + 0x7fffu + ((u >> 16) & 1u)) >> 16;
    return (ushort_t)r;
}
__device__ __forceinline__ float bf2f(ushort_t v) {
    return __uint_as_float(((uint_t)v) << 16);
}

__device__ __forceinline__ float fast_rcp(float x) {
#if __has_builtin(__builtin_amdgcn_rcpf)
    return __builtin_amdgcn_rcpf(x);
#else
    return 1.f / x;
#endif
}
__device__ __forceinline__ float sigm(float x) {
    return fast_rcp(1.f + __expf(-x));
}
__device__ __forceinline__ float tanh_fast(float x) {
    return 1.f - 2.f * fast_rcp(1.f + __expf(2.f * x));
}

__device__ __forceinline__ fx4 mfma16(sh8 a, sh8 b, fx4 c) {
    return __builtin_amdgcn_mfma_f32_16x16x32_bf16(a, b, c, 0, 0, 0);
}

// split fp32 pair -> bf16 hi (trunc) + bf16 lo (residual) packed u32s
__device__ __forceinline__ void split2(float a, float b, uint_t& hi, uint_t& lo) {
    const uint_t ua = __float_as_uint(a), ub = __float_as_uint(b);
    hi = (ua >> 16) | (ub & 0xffff0000u);
    const float la = a - __uint_as_float(ua & 0xffff0000u);
    const float lb = b - __uint_as_float(ub & 0xffff0000u);
    const uint_t ula = __float_as_uint(la), ulb = __float_as_uint(lb);
    lo = (ula >> 16) | (ulb & 0xffff0000u);
}

// async global->LDS, 16B per lane
__device__ __forceinline__ void async_g2l(const ushort_t* g, ushort_t* l) {
#if __has_builtin(__builtin_amdgcn_global_load_lds)
    __builtin_amdgcn_global_load_lds(
        (const __attribute__((address_space(1))) unsigned int*)g,
        (__attribute__((address_space(3))) unsigned int*)l, 16, 0, 0);
#else
    *reinterpret_cast<uint4*>(l) = *reinterpret_cast<const uint4*>(g);
#endif
}

#define BAR() asm volatile("s_waitcnt lgkmcnt(0)\n\ts_barrier" ::: "memory")

// consumer-side wait: thread0 polls device-scope, block fence after
__device__ __forceinline__ void wait_flag(uint_t* f) {
    if (threadIdx.x == 0) {
        while (atomicAdd(f, 0u) == 0u) __builtin_amdgcn_s_sleep(8);
    }
    __syncthreads();
    __threadfence();
}

// ---------------------------------------------------------------------------
// Kernel 0: prepack weights (+ zero the proj-ready flags).
//  y=0..2: recurrent W fp32 [k][j] -> bf16 W^T  T[j*256+k]
//  y=3..5: input Wx fp32 -> split bf16 hi/lo W^T; y==3 also zeroes flags
// ---------------------------------------------------------------------------
__global__ __launch_bounds__(256) void prepack_kernel(
    const float* __restrict__ Wz, const float* __restrict__ Wr,
    const float* __restrict__ Wh,
    const float* __restrict__ Xz, const float* __restrict__ Xr,
    const float* __restrict__ Xh,
    ushort_t* __restrict__ Tz, ushort_t* __restrict__ Tr,
    ushort_t* __restrict__ Th,
    ushort_t* __restrict__ Thi, ushort_t* __restrict__ Tlo,
    uint_t* __restrict__ flags)
{
    const int idx = blockIdx.x * 256 + threadIdx.x;  // 0..65535
    const int j = idx >> 8;
    const int k = idx & 255;
    const int y = blockIdx.y;
    if (y < 3) {
        const float* W = (y == 0) ? Wz : (y == 1) ? Wr : Wh;
        ushort_t* T = (y == 0) ? Tz : (y == 1) ? Tr : Th;
        T[idx] = f2bf(W[k * HD + j]);
    } else {
        const int g = y - 3;
        if (g == 0 && idx < 2048) flags[idx] = 0u;
        const float* W = (g == 0) ? Xz : (g == 1) ? Xr : Xh;
        const float wv = W[k * HD + j];
        const ushort_t hi = f2bf(wv);
        Thi[g * 65536 + idx] = hi;
        Tlo[g * 65536 + idx] = f2bf(wv - bf2f(hi));
    }
}

// ---------------------------------------------------------------------------
// FUSED kernel: blocks 0..63 = recurrence (one batch each); blocks 64..2111 =
// projection producers (one (tc,b) chunk of 32 timesteps each, all 3 gates).
// Producer publishes x5 chunk via threadfence + atomicExch(flag).
// Consumer polls its flag once per 32 steps. Deadlock-free by capacity:
// 64 consumer blocks <= 256 CUs; producers never wait, so they always drain.
// Both roles' inner code is bit-identical to the r5/r7 measured versions.
// ---------------------------------------------------------------------------
#define XROW 264   // u16 per proj LDS row (256 + 8 pad; 528B = 33x16B stride)
#define XB_U16 768 // 3*256 per (t,b)

__global__ __launch_bounds__(512, 1) void gru_fused(
    const float* __restrict__ X,
    const ushort_t* __restrict__ Thi, const ushort_t* __restrict__ Tlo,
    const float* __restrict__ bz, const float* __restrict__ br,
    const float* __restrict__ bh,
    const ushort_t* __restrict__ Tz, const ushort_t* __restrict__ Tr,
    const ushort_t* __restrict__ Th,
    ushort_t* __restrict__ x5,         // [t][b][g][j] bf16
    uint_t* __restrict__ flags,        // [32][64] chunk-ready
    float* __restrict__ out)           // [B][T][256] then H_last [B][256]
{
    // carve: proj needs 2*32*264 (Xs hi/lo) + 8192 (ep) = 25088 u16 = 50176B
    //        gru needs 264 + 264 + 2*768 = 2064 u16
    __shared__ __align__(16) ushort_t smem[25088];

    const int tid  = threadIdx.x;
    const int lane = tid & 63;
    const int w    = tid >> 6;       // wave 0..7
    const int kq   = lane >> 4;
    const int ml   = lane & 15;

    if (blockIdx.x >= 64) {
        // =================== PROJ ROLE (producer) ===========================
        const int pb = blockIdx.x - 64;   // 0..2047
        const int b  = pb & 63;
        const int tc = pb >> 6;           // chunk 0..31
        const int t0 = tc * 32;

        ushort_t* Xs0 = smem;             // hi  [32][XROW]
        ushort_t* Xs1 = smem + 32 * XROW; // lo  [32][XROW]
        ushort_t* ep  = smem + 64 * XROW; // [32*256]

        // ---- load X rows [32][256] fp32, split -> Xs hi/lo ----
#pragma unroll
        for (int i = 0; i < 4; ++i) {
            const int idx = i * 512 + tid;   // 0..2047 float4s
            const int r   = idx >> 6;
            const int c4  = idx & 63;
            const float4 v = *reinterpret_cast<const float4*>(
                X + (size_t)(b * 1024 + t0 + r) * II + c4 * 4);
            uint_t h0, l0, h1, l1;
            split2(v.x, v.y, h0, l0);
            split2(v.z, v.w, h1, l1);
            *reinterpret_cast<uint_t*>(&Xs0[r * XROW + c4 * 4])     = h0;
            *reinterpret_cast<uint_t*>(&Xs0[r * XROW + c4 * 4 + 2]) = h1;
            *reinterpret_cast<uint_t*>(&Xs1[r * XROW + c4 * 4])     = l0;
            *reinterpret_cast<uint_t*>(&Xs1[r * XROW + c4 * 4 + 2]) = l1;
        }
        __syncthreads();

        const fx4 zero4 = {0.f, 0.f, 0.f, 0.f};
        fx4 acc[3][2][2];  // [g][mt][nt]
#pragma unroll
        for (int g = 0; g < 3; ++g)
#pragma unroll
            for (int mt = 0; mt < 2; ++mt)
#pragma unroll
                for (int nt = 0; nt < 2; ++nt) acc[g][mt][nt] = zero4;

#pragma unroll
        for (int kt = 0; kt < 8; ++kt) {
            const int koff = kq * 8 + kt * 32;
            sh8 ahi[2], alo[2];
#pragma unroll
            for (int mt = 0; mt < 2; ++mt) {
                ahi[mt] = *reinterpret_cast<const sh8*>(
                    &Xs0[(mt * 16 + ml) * XROW + koff]);
                alo[mt] = *reinterpret_cast<const sh8*>(
                    &Xs1[(mt * 16 + ml) * XROW + koff]);
            }
#pragma unroll
            for (int g = 0; g < 3; ++g) {
                sh8 bhi[2], blo[2];
#pragma unroll
                for (int nt = 0; nt < 2; ++nt) {
                    const size_t rb = ((size_t)g << 16) +
                        (size_t)(w * 32 + nt * 16 + ml) * 256 + koff;
                    bhi[nt] = *reinterpret_cast<const sh8*>(Thi + rb);
                    blo[nt] = *reinterpret_cast<const sh8*>(Tlo + rb);
                }
#pragma unroll
                for (int mt = 0; mt < 2; ++mt)
#pragma unroll
                    for (int nt = 0; nt < 2; ++nt) {
                        acc[g][mt][nt] = mfma16(ahi[mt], bhi[nt], acc[g][mt][nt]);
                        acc[g][mt][nt] = mfma16(alo[mt], bhi[nt], acc[g][mt][nt]);
                        acc[g][mt][nt] = mfma16(ahi[mt], blo[nt], acc[g][mt][nt]);
                    }
            }
        }

        // ---- epilogue per gate: bias + bf16 via ep staging ----
        for (int g = 0; g < 3; ++g) {
            const float* bias = (g == 0) ? bz : (g == 1) ? br : bh;
            __syncthreads();
#pragma unroll
            for (int nt = 0; nt < 2; ++nt) {
                const int col = w * 32 + nt * 16 + ml;
                const float bv = bias[col];
#pragma unroll
                for (int mt = 0; mt < 2; ++mt)
#pragma unroll
                    for (int r = 0; r < 4; ++r)
                        ep[(mt * 16 + kq * 4 + r) * 256 + col] =
                            f2bf(acc[g][mt][nt][r] + bv);
            }
            __syncthreads();
            const uint4* eps = reinterpret_cast<const uint4*>(ep);
#pragma unroll
            for (int it = 0; it < 2; ++it) {
                const int idx  = it * 512 + tid;  // 0..1023
                const int rr   = idx >> 5;
                const int part = idx & 31;
                uint4* dst = reinterpret_cast<uint4*>(
                    x5 + ((size_t)(t0 + rr) * 64 + b) * 768 + g * 256) + part;
                *dst = eps[idx];
            }
        }

        // publish: __syncthreads drains all stores (vmcnt 0), then flag
        __syncthreads();
        if (tid == 0) {
            __threadfence();
            atomicExch(&flags[pb], 1u);
        }
        return;
    }

    // ===================== GRU ROLE (consumer) ==============================
    const int cl   = lane & 31;     // epilogue column within wave
    const int gate = lane >> 5;     // 0: z-duty, 1: r-duty
    const int sel  = (lane >> 4) & 1;
    const int j    = w * 32 + cl;   // hidden column this lane handles
    const int b    = blockIdx.x;    // batch 0..63

    ushort_t* Hl  = smem;           // 264
    ushort_t* Rl  = smem + 264;     // 264
    ushort_t* Xb0 = smem + 528;     // 768
    ushort_t* Xb1 = smem + 1296;    // 768

    // ---- all three W^T in regs: 3 x 2 x 8 x 4 = 192 ----
    sh8 wz[2][8], wr[2][8], wh[2][8];
#pragma unroll
    for (int cc = 0; cc < 2; ++cc) {
        const int jw = w * 32 + cc * 16 + ml;
        const size_t rb = (size_t)jw * 256 + kq * 8;
#pragma unroll
        for (int kt = 0; kt < 8; ++kt) {
            wz[cc][kt] = *reinterpret_cast<const sh8*>(Tz + rb + kt * 32);
            wr[cc][kt] = *reinterpret_cast<const sh8*>(Tr + rb + kt * 32);
            wh[cc][kt] = *reinterpret_cast<const sh8*>(Th + rb + kt * 32);
        }
    }

    if (tid < 132) { ((uint_t*)Hl)[tid] = 0u; ((uint_t*)Rl)[tid] = 0u; }

    float hk = 0.f;  // lanes 0-31: H[b][j]; lanes 32-63 unused

    // wait for chunk 0 of this batch, then stage x[0]
    wait_flag(&flags[b]);
    if (tid < 96) async_g2l(x5 + (size_t)b * XB_U16 + tid * 8, Xb0 + tid * 8);
    asm volatile("s_waitcnt vmcnt(0)" ::: "memory");
    __syncthreads();

    const ushort_t* harow = Hl + kq * 8;
    const ushort_t* rarow = Rl + kq * 8;
    float* ob = out + (size_t)b * TT * HD;

    const fx4 zero4 = {0.f, 0.f, 0.f, 0.f};
    int cur = 0;
    for (int t = 0; t < TT; ++t) {
        {
            const int tn = (t < TT - 1) ? t + 1 : t;
            if ((tn & 31) == 0 && t < TT - 1)
                wait_flag(&flags[(tn >> 5) * 64 + b]);  // uniform condition
            ushort_t* l = cur ? Xb0 : Xb1;
            if (tid < 96)
                async_g2l(x5 + ((size_t)tn * 64 + b) * XB_U16 + tid * 8,
                          l + tid * 8);
        }
        const ushort_t* xc = cur ? Xb1 : Xb0;

        // hoisted: h[j] into r-lanes + x reads; hidden under phase-1 MFMAs
        const float hsh  = __shfl(hk, cl);
        const float xg   = bf2f(xc[gate * 256 + j]);
        const float xh_r = bf2f(xc[512 + j]);

        // ---- phase 1: Z, R = sigmoid(x + H @ W) ----
        fx4 az0 = zero4, az1 = zero4, ar0 = zero4, ar1 = zero4;
#pragma unroll
        for (int kt = 0; kt < 8; ++kt) {
            const sh8 a = *reinterpret_cast<const sh8*>(harow + kt * 32);
            az0 = mfma16(a, wz[0][kt], az0);
            az1 = mfma16(a, wz[1][kt], az1);
            ar0 = mfma16(a, wr[0][kt], ar0);
            ar1 = mfma16(a, wr[1][kt], ar1);
        }
        const float v0 = gate ? ar0[0] : az0[0];
        const float v1 = gate ? ar1[0] : az1[0];
        const float v  = sel ? v1 : v0;
        const float s  = sigm(xg + v);
        const float zreg = s;  // meaningful in lanes 0-31
        if (gate) Rl[j] = f2bf(s * hsh);
        BAR();  // R*H visible to all waves

        // ---- phase 2: H~ = tanh(xh + (R*H) @ Whh); blend ----
        fx4 ah0a = zero4, ah0b = zero4, ah1a = zero4, ah1b = zero4;
#pragma unroll
        for (int kt = 0; kt < 8; kt += 2) {
            const sh8 a0 = *reinterpret_cast<const sh8*>(rarow + kt * 32);
            const sh8 a1 = *reinterpret_cast<const sh8*>(rarow + (kt + 1) * 32);
            ah0a = mfma16(a0, wh[0][kt], ah0a);
            ah1a = mfma16(a0, wh[1][kt], ah1a);
            ah0b = mfma16(a1, wh[0][kt + 1], ah0b);
            ah1b = mfma16(a1, wh[1][kt + 1], ah1b);
        }
        float hn = hk;
        if (!gate) {  // lanes 0-31 finish their column
            const float va = sel ? (ah1a[0] + ah1b[0]) : (ah0a[0] + ah0b[0]);
            const float th = tanh_fast(xh_r + va);
            hn = zreg * hk + (1.f - zreg) * th;
            hk = hn;
            Hl[j] = f2bf(hn);
        }
        asm volatile("s_waitcnt vmcnt(0)" ::: "memory");  // x[t+1] staged
        BAR();  // H + x-buffer safe for next step

        if (!gate) ob[(size_t)t * HD + j] = hn;
        cur ^= 1;
    }

    if (!gate) out[(size_t)BB * TT * HD + (size_t)b * HD + j] = hk;
}

// ---------------------------------------------------------------------------
extern "C" void kernel_launch(void* const* d_in, const int* in_sizes, int n_in,
                              void* d_out, int out_size, void* d_ws, size_t ws_size,
                              hipStream_t stream) {
    const float* X   = (const float*)d_in[0];
    const float* Wxz = (const float*)d_in[1];
    const float* Whz = (const float*)d_in[2];
    const float* bz  = (const float*)d_in[3];
    const float* Wxr = (const float*)d_in[4];
    const float* Whr = (const float*)d_in[5];
    const float* br  = (const float*)d_in[6];
    const float* Wxh = (const float*)d_in[7];
    const float* Whh = (const float*)d_in[8];
    const float* bh  = (const float*)d_in[9];
    float* out = (float*)d_out;

    // ws: x5 (96MiB) | Tz/Tr/Th (3x128KiB) | Thi (384KiB) | Tlo (384KiB) | flags
    const size_t X5_BYTES = (size_t)TT * BB * 3 * 256 * 2;
    ushort_t* x5  = (ushort_t*)d_ws;
    ushort_t* Tz  = (ushort_t*)((char*)d_ws + X5_BYTES);
    ushort_t* Tr  = Tz + HD * HD;
    ushort_t* Th  = Tr + HD * HD;
    ushort_t* Thi = Th + HD * HD;            // 3 * 65536 u16
    ushort_t* Tlo = Thi + 3 * HD * HD;       // 3 * 65536 u16
    uint_t*   flags = (uint_t*)(Tlo + 3 * HD * HD);  // 2048 u32

    prepack_kernel<<<dim3(256, 6), 256, 0, stream>>>(
        Whz, Whr, Whh, Wxz, Wxr, Wxh, Tz, Tr, Th, Thi, Tlo, flags);
    gru_fused<<<dim3(64 + 2048), 512, 0, stream>>>(
        X, Thi, Tlo, bz, br, bh, Tz, Tr, Th, x5, flags, out);
}